// Round 5
// baseline (524.421 us; speedup 1.0000x reference)
//
#include <hip/hip_runtime.h>
#include <math.h>

#define B_ 128
#define T_ 256
#define N_ 16
#define K_ 10
#define H_ 20
#define TN_ 4096     // T_*N_
#define TSLAB_ 32    // t's per block
#define NTC_ 8       // T_/TSLAB_

#define REP20(F) F(0) F(1) F(2) F(3) F(4) F(5) F(6) F(7) F(8) F(9) \
                 F(10) F(11) F(12) F(13) F(14) F(15) F(16) F(17) F(18) F(19)

__device__ __forceinline__ float wsum(float v)
{
#pragma unroll
    for (int off = 32; off; off >>= 1) v += __shfl_xor(v, off);
    return v;
}

// ---------------------------------------------------------------------------
// ONE fused kernel. Block = (kn = k*16+n, tc = 32-t slab). 256 thr = 4 waves.
//   P0: stage x[:, t-slab, n] into LDS transposed [t_local][b].
//   P2: per wave, 8 t-columns: standardize over b in-reg (ddof=1, no eps),
//       MLP with BLOCK-UNIFORM weights (scalar s_load pipe), 2 samples/lane,
//       standardize t over b (ddof=1, std+1e-8), store z to global ws.
//   P3: last of the 16 n-blocks per (k,tc) [ticket] computes the product
//       phase for its 32 t's and atomicAdds into a ws accumulator; the last
//       of the 80 winners copies the total to out.
// Product of 16 marginal means (fp32 rounding residue after standardization)
// underflows to 0 in the fp32 reference => penalty = pj^2 (verified R2-R4).
// __launch_bounds__(256,1): let the allocator keep h/g in VGPRs (AGPR-copy
// bloat theory: VGPR_Count=24 with 40 live floats in R2/R3).
// ---------------------------------------------------------------------------
__global__ __launch_bounds__(256, 1) void k_fused(
    const float* __restrict__ x,
    const float* __restrict__ W1, const float* __restrict__ b1,
    const float* __restrict__ W2, const float* __restrict__ b2,
    const float* __restrict__ W3, const float* __restrict__ b3,
    float* __restrict__ out,
    unsigned int* __restrict__ tickets,   // ws: 80 u32, zeroed
    unsigned int* __restrict__ done,      // ws: 1 u32, zeroed
    float* __restrict__ acc,              // ws: 1 f32, zeroed
    float* __restrict__ zbuf)             // ws: [K][T][N][B] f32
{
    __shared__ float xz[TSLAB_ * 129];    // [t_local][b], pad 129
    __shared__ float wred[4];
    __shared__ int   flag;

    const int tc  = blockIdx.x;           // 0..7
    const int kn  = blockIdx.y;           // 0..159
    const int k   = kn >> 4;
    const int n   = kn & 15;
    const int tid = threadIdx.x;
    const int wv  = tid >> 6;
    const int l   = tid & 63;

    // ---- P0: stage x slab (all b, 32 t, fixed n) into LDS [t][b] ----
#pragma unroll
    for (int it = 0; it < 16; ++it) {
        const int e   = it * 256 + tid;   // 0..4095
        const int col = e >> 7;           // t_local
        const int b   = e & 127;
        xz[col * 129 + b] = x[b * TN_ + (tc * TSLAB_ + col) * N_ + n];
    }
    __syncthreads();

    // block-uniform weight bases -> scalar loads
    const float* __restrict__ w1c = W1 + kn * H_;
    const float* __restrict__ b1c = b1 + kn * H_;
    const float* __restrict__ w2c = W2 + kn * H_ * H_;
    const float* __restrict__ b2c = b2 + kn * H_;
    const float* __restrict__ w3c = W3 + kn * H_;
    const float  bb3 = b3[kn];

    // ---- P2: per wave: 8 t-columns ----
#pragma unroll 1
    for (int it = 0; it < 8; ++it) {
        const int col = wv * 8 + it;      // t_local
        const int tg  = tc * TSLAB_ + col;

        // standardize x column over b (ddof=1, no eps), in-register
        const float a0 = xz[col * 129 + l];
        const float a1 = xz[col * 129 + 64 + l];
        const float xmu = wsum(a0 + a1) * (1.f / 128.f);
        const float xd0 = a0 - xmu, xd1 = a1 - xmu;
        const float xr  = __builtin_amdgcn_rsqf(wsum(fmaf(xd0, xd0, xd1 * xd1)) * (1.f / 127.f));
        const float u0 = xd0 * xr, u1 = xd1 * xr;

        // Layer 1 + ReLU
#define DECLH(i) float ha##i, hb##i;
        REP20(DECLH)
        float s1a = 0.f, s1b = 0.f;
#define L1(i) { const float w = w1c[i], bb = b1c[i]; \
        ha##i = fmaxf(fmaf(u0, w, bb), 0.f); s1a += ha##i; \
        hb##i = fmaxf(fmaf(u1, w, bb), 0.f); s1b += hb##i; }
        REP20(L1)

        // LayerNorm 1 (biased var, eps 1e-5)
        const float mu1a = s1a * 0.05f, mu1b = s1b * 0.05f;
        float v1a = 0.f, v1b = 0.f;
#define VAR1(i) { float d = ha##i - mu1a; v1a = fmaf(d, d, v1a); d = hb##i - mu1b; v1b = fmaf(d, d, v1b); }
        REP20(VAR1)
        const float r1a = __builtin_amdgcn_rsqf(v1a * 0.05f + 1e-5f);
        const float r1b = __builtin_amdgcn_rsqf(v1b * 0.05f + 1e-5f);
        const float m1a = mu1a * r1a, m1b = mu1b * r1b;
#define NRM1(i) ha##i = fmaf(ha##i, r1a, -m1a); hb##i = fmaf(hb##i, r1b, -m1b);
        REP20(NRM1)

        // Layer 2 (20x20) + ReLU
#define DECLG(i) float ga##i, gb##i;
        REP20(DECLG)
        float s2a = 0.f, s2b = 0.f;
#define L2I(o,i) { const float w = w2c[(o) * 20 + (i)]; \
        acca = fmaf(ha##i, w, acca); accb = fmaf(hb##i, w, accb); }
#define L2ALL(o) L2I(o,0) L2I(o,1) L2I(o,2) L2I(o,3) L2I(o,4) \
        L2I(o,5) L2I(o,6) L2I(o,7) L2I(o,8) L2I(o,9) \
        L2I(o,10) L2I(o,11) L2I(o,12) L2I(o,13) L2I(o,14) \
        L2I(o,15) L2I(o,16) L2I(o,17) L2I(o,18) L2I(o,19)
#define L2ROW(o) { float acca = b2c[o], accb = acca; L2ALL(o) \
        ga##o = fmaxf(acca, 0.f); s2a += ga##o; \
        gb##o = fmaxf(accb, 0.f); s2b += gb##o; }
        REP20(L2ROW)

        // LayerNorm 2 fused into layer-3 dot
        const float mu2a = s2a * 0.05f, mu2b = s2b * 0.05f;
        float v2a = 0.f, v2b = 0.f;
#define VAR2(i) { float d = ga##i - mu2a; v2a = fmaf(d, d, v2a); d = gb##i - mu2b; v2b = fmaf(d, d, v2b); }
        REP20(VAR2)
        const float r2a = __builtin_amdgcn_rsqf(v2a * 0.05f + 1e-5f);
        const float r2b = __builtin_amdgcn_rsqf(v2b * 0.05f + 1e-5f);
        const float m2a = mu2a * r2a, m2b = mu2b * r2b;

        float t0 = bb3, t1 = bb3;
#define L3(i) { const float w = w3c[i]; \
        t0 = fmaf(fmaf(ga##i, r2a, -m2a), w, t0); \
        t1 = fmaf(fmaf(gb##i, r2b, -m2b), w, t1); }
        REP20(L3)

        // standardize t over b (ddof=1, std+1e-8), store z to global
        const float smu = wsum(t0 + t1) * (1.f / 128.f);
        const float e0 = t0 - smu, e1 = t1 - smu;
        const float sd = sqrtf(wsum(fmaf(e0, e0, e1 * e1)) * (1.f / 127.f));
        const float rr = 1.f / (sd + 1e-8f);
        float* zg = zbuf + (((size_t)k * T_ + tg) * N_ + n) * B_;
        zg[l]      = e0 * rr;
        zg[64 + l] = e1 * rr;
    }

    // ---- ticket: last of 16 n-blocks for (k,tc) does the product phase ----
    __syncthreads();                       // all z stores drained (vmcnt(0))
    if (tid == 0) {
        __threadfence();                   // release: z visible device-wide
        const unsigned int old = atomicAdd(&tickets[k * NTC_ + tc], 1u);
        flag = (old == 15u);
    }
    __syncthreads();
    if (!flag) return;

    if (tid == 0) __threadfence();         // acquire side
    __syncthreads();

    // ---- P3: products over n for 32 t's; penalty = sum pj^2 ----
    float part = 0.f;
#pragma unroll 1
    for (int c = 0; c < 8; ++c) {
        const int tg = tc * TSLAB_ + wv * 8 + c;
        const float* __restrict__ zrow = zbuf + ((size_t)k * T_ + tg) * (N_ * B_);
        float p0 = zrow[l], p1 = zrow[64 + l];
#pragma unroll
        for (int nn = 1; nn < N_; ++nn) {
            p0 *= zrow[nn * B_ + l];
            p1 *= zrow[nn * B_ + 64 + l];
        }
        const float pj = wsum(p0 + p1) * (1.f / 128.f);
        part += pj * pj;
    }
    if (l == 0) wred[wv] = part;
    __syncthreads();

    if (tid == 0) {
        const float s = (wred[0] + wred[1] + wred[2] + wred[3]) * (1.f / (K_ * T_));
        atomicAdd(acc, s);
        __threadfence();                   // order acc-add before done-add
        const unsigned int d = atomicAdd(done, 1u);
        if (d == 79u) {                    // last of 80 winners
            const float tot = atomicAdd(acc, 0.f);   // device-scope read
            out[0] = tot;
        }
    }
}

// ---------------------------------------------------------------------------
extern "C" void kernel_launch(void* const* d_in, const int* in_sizes, int n_in,
                              void* d_out, int out_size, void* d_ws, size_t ws_size,
                              hipStream_t stream)
{
    const float* x  = (const float*)d_in[0];
    const float* W1 = (const float*)d_in[1];
    const float* b1 = (const float*)d_in[2];
    const float* W2 = (const float*)d_in[3];
    const float* b2 = (const float*)d_in[4];
    const float* W3 = (const float*)d_in[5];
    const float* b3 = (const float*)d_in[6];
    float* out = (float*)d_out;

    char* ws = (char*)d_ws;
    unsigned int* tickets = (unsigned int*)ws;            // 80 u32
    unsigned int* done    = (unsigned int*)(ws + 384);    // 1 u32
    float*        acc     = (float*)(ws + 512);           // 1 f32
    float*        zbuf    = (float*)(ws + 4096);          // 20 MB [K][T][N][B]

    hipMemsetAsync(ws, 0, 1024, stream);                  // tickets+done+acc

    dim3 grid(NTC_, K_ * N_);                             // 8 x 160
    k_fused<<<grid, 256, 0, stream>>>(x, W1, b1, W2, b2, W3, b3,
                                      out, tickets, done, acc, zbuf);
}